// Round 11
// baseline (9340.278 us; speedup 1.0000x reference)
//
#include <hip/hip_runtime.h>
#include <math.h>

#define T_SEQ 4096
typedef unsigned long long ull;

__device__ __forceinline__ float sigmoidf_(float x) {
  return 1.0f / (1.0f + expf(-x));
}

__device__ __forceinline__ ull pack_h(int tag, float h) {
  return ((ull)(unsigned)tag << 32) | (ull)__float_as_uint(h);
}

// System-scope (MALL) exchange — the only always-fresh primitives validated
// this session (R0-R9). vmcnt(0) INSIDE the asm is load-bearing: no load
// escapes the statement (R9's NaN = probes left in flight). R10 lesson:
// poller lanes must live in waves that NEVER store (vmcnt drains in order
// per wave, so a co-resident publish ack serializes into every probe).
__device__ __forceinline__ ull ld_mall(const ull* p) {
  ull v;
  asm volatile("global_load_dwordx2 %0, %1, off sc0 sc1\n\ts_waitcnt vmcnt(0)"
               : "=v"(v) : "v"(p) : "memory");
  return v;
}
__device__ __forceinline__ void st_mall(ull* p, ull v) {
  asm volatile("global_store_dwordx2 %0, %1, off sc0 sc1"
               :: "v"(p), "v"(v) : "memory");
}
__device__ __forceinline__ float poll_mall(const ull* p, unsigned want) {
  for (;;) {
    ull v = ld_mall(p);
    if ((unsigned)(v >> 32) == want) return __uint_as_float((unsigned)v);
  }
}

// Raw workgroup barrier: drains LDS (lgkm) only — publishes/probes stay in
// flight across it.
__device__ __forceinline__ void bar() {
  asm volatile("s_waitcnt lgkmcnt(0)" ::: "memory");
  __builtin_amdgcn_s_barrier();
  asm volatile("" ::: "memory");
}

// ---- named-register weight fragments + anti-rematerialization pin ----------
#define DECL_W8(p) float4 p##0, p##1, p##2, p##3, p##4, p##5, p##6, p##7
#define LOAD_W8(p, src) do { const float4* _s = (const float4*)(src); \
  p##0=_s[0]; p##1=_s[1]; p##2=_s[2]; p##3=_s[3]; \
  p##4=_s[4]; p##5=_s[5]; p##6=_s[6]; p##7=_s[7]; } while (0)
#define PIN4(v4) asm volatile("" : "+v"((v4).x), "+v"((v4).y), \
                                   "+v"((v4).z), "+v"((v4).w))
#define PIN_W8(p) do { PIN4(p##0); PIN4(p##1); PIN4(p##2); PIN4(p##3); \
  PIN4(p##4); PIN4(p##5); PIN4(p##6); PIN4(p##7); } while (0)
#define FMA4(acc, W_, H_) do { acc = fmaf((W_).x, (H_).x, acc); \
  acc = fmaf((W_).y, (H_).y, acc); acc = fmaf((W_).z, (H_).z, acc); \
  acc = fmaf((W_).w, (H_).w, acc); } while (0)
#define G8(acc, p, h4) do { \
  { float4 hv = (h4)[0]; FMA4(acc, p##0, hv); } \
  { float4 hv = (h4)[1]; FMA4(acc, p##1, hv); } \
  { float4 hv = (h4)[2]; FMA4(acc, p##2, hv); } \
  { float4 hv = (h4)[3]; FMA4(acc, p##3, hv); } \
  { float4 hv = (h4)[4]; FMA4(acc, p##4, hv); } \
  { float4 hv = (h4)[5]; FMA4(acc, p##5, hv); } \
  { float4 hv = (h4)[6]; FMA4(acc, p##6, hv); } \
  { float4 hv = (h4)[7]; FMA4(acc, p##7, hv); } \
} while (0)

// Quad gate combine: rows m = cell*4 + gate, lane base+{0,1,2,3} hold
// act(i,f,g,o). Verified algebra (R6/R7/R10, HW-passed 3x).
#define QUAD_COMBINE(tt, act, i_, f_, g_, o_) \
  float y  = __shfl_xor(act, 1); \
  float zx = __shfl_xor(act, 2); \
  float zy = __shfl_xor(y, 2); \
  const bool l1b = ((tt) & 1), h1b = ((tt) & 2); \
  float i_ = h1b ? (l1b ? zy : zx) : (l1b ? y : act); \
  float f_ = h1b ? (l1b ? zx : zy) : (l1b ? act : y); \
  float g_ = h1b ? (l1b ? y : act) : (l1b ? zy : zx); \
  float o_ = h1b ? (l1b ? act : y) : (l1b ? zx : zy);

// X[t][k] = emb[tokens[t]][k], as float4
__global__ void gather_emb(const int* __restrict__ tokens,
                           const float4* __restrict__ emb4,
                           float4* __restrict__ X4) {
  int i = blockIdx.x * 256 + threadIdx.x;   // i < 4096*128
  int t = i >> 7;
  int q = i & 127;
  X4[i] = emb4[(long)tokens[t] * 128 + q];
}

// P[t][j] = bias_ih[j] + bias_hh[j] + sum_k X[src(t)][k] * W[j][k]
__global__ __launch_bounds__(256) void gemm_proj(
    const float* __restrict__ Xf, const float* __restrict__ Xb, int revb,
    const float* __restrict__ Wf, const float* __restrict__ Wb,
    const float* __restrict__ bihf, const float* __restrict__ bhhf,
    const float* __restrict__ bihb, const float* __restrict__ bhhb,
    float* __restrict__ Pf, float* __restrict__ Pb, int K)
{
  const int dirb = blockIdx.z;
  const float* X  = dirb ? Xb : Xf;
  const float* W  = dirb ? Wb : Wf;
  const float* bih = dirb ? bihb : bihf;
  const float* bhh = dirb ? bhhb : bhhf;
  float* Pp = dirb ? Pb : Pf;
  const int rev = dirb ? revb : 0;

  const int bn = blockIdx.x;
  const int bm = blockIdx.y;
  const int tid = threadIdx.x;
  const int tx = tid & 15, ty = tid >> 4;

  __shared__ float Xs[16][68];
  __shared__ float Ws[16][68];

  float acc[4][4] = {{0.f}};

  const int lrow = tid >> 2;
  const int lk4  = (tid & 3) * 4;
  const int xrow = bm * 64 + lrow;
  const int xsrc = rev ? (4095 - xrow) : xrow;
  const float* xptr = X + (long)xsrc * K + lk4;
  const float* wptr = W + (long)(bn * 64 + lrow) * K + lk4;

  for (int k0 = 0; k0 < K; k0 += 16) {
    float4 xv = *(const float4*)(xptr + k0);
    float4 wv = *(const float4*)(wptr + k0);
    __syncthreads();
    Xs[lk4 + 0][lrow] = xv.x; Xs[lk4 + 1][lrow] = xv.y;
    Xs[lk4 + 2][lrow] = xv.z; Xs[lk4 + 3][lrow] = xv.w;
    Ws[lk4 + 0][lrow] = wv.x; Ws[lk4 + 1][lrow] = wv.y;
    Ws[lk4 + 2][lrow] = wv.z; Ws[lk4 + 3][lrow] = wv.w;
    __syncthreads();
    #pragma unroll
    for (int kk = 0; kk < 16; ++kk) {
      float4 a = *(const float4*)(&Xs[kk][ty * 4]);
      float4 b = *(const float4*)(&Ws[kk][tx * 4]);
      acc[0][0] = fmaf(a.x, b.x, acc[0][0]); acc[0][1] = fmaf(a.x, b.y, acc[0][1]);
      acc[0][2] = fmaf(a.x, b.z, acc[0][2]); acc[0][3] = fmaf(a.x, b.w, acc[0][3]);
      acc[1][0] = fmaf(a.y, b.x, acc[1][0]); acc[1][1] = fmaf(a.y, b.y, acc[1][1]);
      acc[1][2] = fmaf(a.y, b.z, acc[1][2]); acc[1][3] = fmaf(a.y, b.w, acc[1][3]);
      acc[2][0] = fmaf(a.z, b.x, acc[2][0]); acc[2][1] = fmaf(a.z, b.y, acc[2][1]);
      acc[2][2] = fmaf(a.z, b.z, acc[2][2]); acc[2][3] = fmaf(a.z, b.w, acc[2][3]);
      acc[3][0] = fmaf(a.w, b.x, acc[3][0]); acc[3][1] = fmaf(a.w, b.y, acc[3][1]);
      acc[3][2] = fmaf(a.w, b.z, acc[3][2]); acc[3][3] = fmaf(a.w, b.w, acc[3][3]);
    }
  }

  const int c0 = bn * 64 + tx * 4;
  #pragma unroll
  for (int i = 0; i < 4; ++i) {
    const int r = bm * 64 + ty * 4 + i;
    float4 o4;
    o4.x = acc[i][0] + bih[c0 + 0] + bhh[c0 + 0];
    o4.y = acc[i][1] + bih[c0 + 1] + bhh[c0 + 1];
    o4.z = acc[i][2] + bih[c0 + 2] + bhh[c0 + 2];
    o4.w = acc[i][3] + bih[c0 + 3] + bhh[c0 + 3];
    *(float4*)(&Pp[(long)r * 1024 + c0]) = o4;
  }
}

// Fused 2-layer bidirectional LSTM with DIRECTION INTERLEAVING: the f and b
// chains are independent serial recurrences; each WG owns cells of BOTH and
// alternates f-step / b-step, so each chain's exchange latency L hides under
// the other chain's compute+wait. Steady state: two steps per (L + C) —
// per-step cost halves vs R6.
//   bx 0-7  : L0, 32f+32b cells each (8x32=256/dir). 1024 thr.
//   bx 8-23 : L1, 16f+16b cells each (16x16=256/dir). 1024 thr.
// Wave roles (R10 lesson — pollers never share a wave with any store):
//   L0: C+publish t<128 (waves 0-1); pollers t in [256,480) (waves 4-7).
//   L1: C+publish t<64  (wave 0);    pollers t in [64,560)  (waves 1-8).
// Per-chain body = R6's proven shape: poll -> bar -> part[] matvec -> bar ->
// activation + quad combine + publish.
__global__ __launch_bounds__(1024, 1) void lstm_fused(
    const float* __restrict__ P0f, const float* __restrict__ P0b,
    const float* __restrict__ Whh0f, const float* __restrict__ Whh0b,
    const float* __restrict__ Wih1f, const float* __restrict__ Whh1f,
    const float* __restrict__ bih1f, const float* __restrict__ bhh1f,
    const float* __restrict__ Wih1b, const float* __restrict__ Whh1b,
    const float* __restrict__ bih1b, const float* __restrict__ bhh1b,
    float* __restrict__ out,
    ull* __restrict__ ring0,    // h0 rings [2 dirs][4096][256]
    ull* __restrict__ h1x)      // h1 slots [2 dirs][2 par][256]
{
  const int bx = blockIdx.x;
  const int t  = threadIdx.x;

  __shared__ __align__(16) float hxf[512];   // L0: h[256] | L1: h0[256]+h1[256]
  __shared__ __align__(16) float hxb[512];
  __shared__ __align__(16) float part[1152];

  ull* ringf = ring0;
  ull* ringb = ring0 + (long)T_SEQ * 256;

  if (bx < 8) {
    // ======================= Layer 0 (8 WGs, 32f+32b cells) =================
    const int w = bx, wbase = w * 32;
    const int kb = t >> 7;      // k-slice 0..7 (32 k each)
    const int m  = t & 127;     // row = cell*4 + gate
    const int j  = (m & 3) * 256 + wbase + (m >> 2);

    DECL_W8(wf); DECL_W8(wg);
    LOAD_W8(wf, Whh0f + (long)j * 256 + kb * 32);
    LOAD_W8(wg, Whh0b + (long)j * 256 + kb * 32);
    PIN_W8(wf); PIN_W8(wg);

    const int isC = (t < 128);
    const long pj = (long)((t & 3) * 256 + wbase + (t >> 2));
    const int pol = (t >= 256 && t < 480);
    const int q   = t - 256;
    const int pcell = (q < wbase) ? q : q + 32;

    float pvf = 0.f, pvb = 0.f, cf = 0.f, cb = 0.f;
    if (isC) { pvf = P0f[pj]; pvb = P0b[pj]; }
    if (t < 256) { hxf[t] = 0.f; hxb[t] = 0.f; }
    bar();

    for (int s = 0; s < T_SEQ; ++s) {
      // ================= F chain, step s =================
      float pvfn = 0.f;
      if (isC && s + 1 < T_SEQ) pvfn = P0f[(long)(s + 1) * 1024 + pj];
      if (pol && s > 0)
        hxf[pcell] = poll_mall(ringf + (long)(s - 1) * 256 + pcell, (unsigned)s);
      bar();   // Y_f: hxf complete
      {
        const float4* h4 = (const float4*)&hxf[kb * 32];
        float a = 0.f; G8(a, wf, h4);
        part[kb * 136 + m] = a;
      }
      bar();   // 2_f: part complete
      if (isC) {
        float g = pvf;
        #pragma unroll
        for (int qq = 0; qq < 8; ++qq) g += part[qq * 136 + t];
        pvf = pvfn;
        float act = ((t & 3) == 2) ? tanhf(g) : sigmoidf_(g);
        QUAD_COMBINE(t, act, i_, f_, g_, o_);
        cf = f_ * cf + i_ * g_;
        float h = o_ * tanhf(cf);
        if ((t & 3) == 0) {
          const int gc = wbase + (t >> 2);
          hxf[gc] = h;                                  // own-cell LDS bypass
          st_mall(ringf + (long)s * 256 + gc, pack_h(s + 1, h));
          if (s == T_SEQ - 1) {
            out[gc] = cf;               // cell_memories L0 f
            out[1024 + gc] = h;         // hidden_states L0 f
          }
        }
      }
      // ================= B chain, step s =================
      float pvbn = 0.f;
      if (isC && s + 1 < T_SEQ) pvbn = P0b[(long)(s + 1) * 1024 + pj];
      if (pol && s > 0)
        hxb[pcell] = poll_mall(ringb + (long)(s - 1) * 256 + pcell, (unsigned)s);
      bar();   // Y_b (also orders C_f part-reads vs B_b part-writes)
      {
        const float4* h4 = (const float4*)&hxb[kb * 32];
        float a = 0.f; G8(a, wg, h4);
        part[kb * 136 + m] = a;
      }
      bar();   // 2_b
      if (isC) {
        float g = pvb;
        #pragma unroll
        for (int qq = 0; qq < 8; ++qq) g += part[qq * 136 + t];
        pvb = pvbn;
        float act = ((t & 3) == 2) ? tanhf(g) : sigmoidf_(g);
        QUAD_COMBINE(t, act, i_, f_, g_, o_);
        cb = f_ * cb + i_ * g_;
        float h = o_ * tanhf(cb);
        if ((t & 3) == 0) {
          const int gc = wbase + (t >> 2);
          hxb[gc] = h;
          st_mall(ringb + (long)s * 256 + gc, pack_h(s + 1, h));
          if (s == T_SEQ - 1) {
            out[256 + gc] = cb;         // cell_memories L0 b
            out[1280 + gc] = h;         // hidden_states L0 b
          }
        }
      }
    }
  } else {
    // ======================= Layer 1 (16 WGs, 16f+16b cells) ================
    const int w1 = bx - 8, wb1 = w1 * 16;
    const int kb = t >> 6;      // k-slice 0..15 (32 k of combined K=512)
    const int m  = t & 63;      // row = cell*4 + gate
    const int j  = (m & 3) * 256 + wb1 + (m >> 2);

    DECL_W8(uf); DECL_W8(ug);
    {
      const float* sf = (kb < 8) ? (Wih1f + (long)j * 256 + kb * 32)
                                 : (Whh1f + (long)j * 256 + (kb - 8) * 32);
      const float* sb = (kb < 8) ? (Wih1b + (long)j * 256 + kb * 32)
                                 : (Whh1b + (long)j * 256 + (kb - 8) * 32);
      LOAD_W8(uf, sf); LOAD_W8(ug, sb);
      PIN_W8(uf); PIN_W8(ug);
    }

    const int isC = (t < 64);
    float bsf = 0.f, bsb = 0.f, cf = 0.f, cb = 0.f;
    if (isC) {
      const int jc = (t & 3) * 256 + wb1 + (t >> 2);
      bsf = bih1f[jc] + bhh1f[jc];
      bsb = bih1b[jc] + bhh1b[jc];
    }
    const int h0p = (t >= 64 && t < 320);     // h0 pollers
    const int c0_ = t - 64;
    const int sbp = (t >= 320 && t < 560);    // h1-sibling pollers
    const int q1  = t - 320;
    const int pc1 = (q1 < wb1) ? q1 : q1 + 16;

    ull* slotf = h1x;           // [parity][256]
    ull* slotb = h1x + 512;
    float* houtf = out + 2048;
    float* houtb = out + 2048 + (long)4095 * 512 + 256;

    if (t < 512) { hxf[t] = 0.f; hxb[t] = 0.f; }
    bar();

    for (int s = 0; s < T_SEQ; ++s) {
      // ================= F chain, step s =================
      if (h0p) hxf[c0_] = poll_mall(ringf + (long)s * 256 + c0_, (unsigned)(s + 1));
      if (sbp && s > 0)
        hxf[256 + pc1] = poll_mall(slotf + (long)((s + 1) & 1) * 256 + pc1,
                                   (unsigned)s);
      bar();   // Y_f
      {
        const float4* h4 = (const float4*)&hxf[kb * 32];
        float a = 0.f; G8(a, uf, h4);
        part[kb * 72 + m] = a;
      }
      bar();   // 2_f
      if (isC) {
        float g = bsf;
        #pragma unroll
        for (int qq = 0; qq < 16; ++qq) g += part[qq * 72 + t];
        float act = ((t & 3) == 2) ? tanhf(g) : sigmoidf_(g);
        QUAD_COMBINE(t, act, i_, f_, g_, o_);
        cf = f_ * cf + i_ * g_;
        float h = o_ * tanhf(cf);
        if ((t & 3) == 0) {
          const int gc = wb1 + (t >> 2);
          hxf[256 + gc] = h;                            // own-cell LDS bypass
          st_mall(&slotf[(long)(s & 1) * 256 + gc], pack_h(s + 1, h));
          houtf[(long)s * 512 + gc] = h;
          if (s == T_SEQ - 1) {
            out[512 + gc] = cf;         // cell_memories L1 f
            out[1536 + gc] = h;         // hidden_states L1 f
          }
        }
      }
      // ================= B chain, step s =================
      if (h0p) hxb[c0_] = poll_mall(ringb + (long)s * 256 + c0_, (unsigned)(s + 1));
      if (sbp && s > 0)
        hxb[256 + pc1] = poll_mall(slotb + (long)((s + 1) & 1) * 256 + pc1,
                                   (unsigned)s);
      bar();   // Y_b
      {
        const float4* h4 = (const float4*)&hxb[kb * 32];
        float a = 0.f; G8(a, ug, h4);
        part[kb * 72 + m] = a;
      }
      bar();   // 2_b
      if (isC) {
        float g = bsb;
        #pragma unroll
        for (int qq = 0; qq < 16; ++qq) g += part[qq * 72 + t];
        float act = ((t & 3) == 2) ? tanhf(g) : sigmoidf_(g);
        QUAD_COMBINE(t, act, i_, f_, g_, o_);
        cb = f_ * cb + i_ * g_;
        float h = o_ * tanhf(cb);
        if ((t & 3) == 0) {
          const int gc = wb1 + (t >> 2);
          hxb[256 + gc] = h;
          st_mall(&slotb[(long)(s & 1) * 256 + gc], pack_h(s + 1, h));
          houtb[(long)s * (-512) + gc] = h;
          if (s == T_SEQ - 1) {
            out[768 + gc] = cb;         // cell_memories L1 b
            out[1792 + gc] = h;         // hidden_states L1 b
          }
        }
      }
    }
  }
}

extern "C" void kernel_launch(void* const* d_in, const int* in_sizes, int n_in,
                              void* d_out, int out_size, void* d_ws, size_t ws_size,
                              hipStream_t stream) {
  const int*   tokens = (const int*)d_in[0];
  const float* emb    = (const float*)d_in[1];
  const float* fWih0 = (const float*)d_in[2];
  const float* fWhh0 = (const float*)d_in[3];
  const float* fbih0 = (const float*)d_in[4];
  const float* fbhh0 = (const float*)d_in[5];
  const float* fWih1 = (const float*)d_in[6];
  const float* fWhh1 = (const float*)d_in[7];
  const float* fbih1 = (const float*)d_in[8];
  const float* fbhh1 = (const float*)d_in[9];
  const float* bWih0 = (const float*)d_in[10];
  const float* bWhh0 = (const float*)d_in[11];
  const float* bbih0 = (const float*)d_in[12];
  const float* bbhh0 = (const float*)d_in[13];
  const float* bWih1 = (const float*)d_in[14];
  const float* bWhh1 = (const float*)d_in[15];
  const float* bbih1 = (const float*)d_in[16];
  const float* bbhh1 = (const float*)d_in[17];

  float* out = (float*)d_out;
  float* ws  = (float*)d_ws;

  // Workspace layout (float offsets):
  //   [0, 4194304)          h0 rings [2 dirs][4096][256] u64 (16 MB); X
  //                         overlaps the first 8 MB (dead after gemm_proj,
  //                         rings memset afterwards)
  //   [4194304,  8388608)   P0f (4096x1024)
  //   [8388608, 12582912)   P0b (4096x1024)
  //   [12582912, 12584960)  h1x [2 dirs][2 par][256] u64 (8 KB)
  float* X   = ws;
  float* P0f = ws + 4194304;
  float* P0b = ws + 8388608;
  ull* ring0 = (ull*)ws;
  ull* h1x   = (ull*)(ws + 12582912);

  gather_emb<<<2048, 256, 0, stream>>>(tokens, (const float4*)emb, (float4*)X);

  // Layer 0 input projections (K=512); b-direction reads X time-reversed.
  gemm_proj<<<dim3(16, 64, 2), 256, 0, stream>>>(
      X, X, 1, fWih0, bWih0, fbih0, fbhh0, bbih0, bbhh0, P0f, P0b, 512);

  // Reset exchange buffers (tag 0 = "not ready" / "h(-1)=0").
  hipMemsetAsync(ring0, 0, (size_t)2 * T_SEQ * 256 * sizeof(ull), stream);
  hipMemsetAsync(h1x, 0, 1024 * sizeof(ull), stream);

  // Fused recurrence: 24 WGs, each interleaving both directions.
  lstm_fused<<<dim3(24), 1024, 0, stream>>>(
      P0f, P0b, fWhh0, bWhh0,
      fWih1, fWhh1, fbih1, fbhh1,
      bWih1, bWhh1, bbih1, bbhh1,
      out, ring0, h1x);
}

// Round 12
// 7063.738 us; speedup vs baseline: 1.3223x; 1.3223x over previous
//
#include <hip/hip_runtime.h>
#include <math.h>

#define T_SEQ 4096
typedef unsigned long long ull;

__device__ __forceinline__ float sigmoidf_(float x) {
  return 1.0f / (1.0f + expf(-x));
}

__device__ __forceinline__ ull pack_h(int tag, float h) {
  return ((ull)(unsigned)tag << 32) | (ull)__float_as_uint(h);
}

// System-scope (MALL) exchange — the only always-fresh primitives validated
// this session (R0-R11): cached probes read stale lines forever; atomics
// serialize per-lane (R7); deep-poll with escaping loads clobbers registers
// (R9); pollers sharing a wave with ANY store serialize on store-acks (R10).
// vmcnt(0) INSIDE the asm is load-bearing.
__device__ __forceinline__ ull ld_mall(const ull* p) {
  ull v;
  asm volatile("global_load_dwordx2 %0, %1, off sc0 sc1\n\ts_waitcnt vmcnt(0)"
               : "=v"(v) : "v"(p) : "memory");
  return v;
}
__device__ __forceinline__ void st_mall(ull* p, ull v) {
  asm volatile("global_store_dwordx2 %0, %1, off sc0 sc1"
               :: "v"(p), "v"(v) : "memory");
}
__device__ __forceinline__ float poll_mall(const ull* p, unsigned want) {
  for (;;) {
    ull v = ld_mall(p);
    if ((unsigned)(v >> 32) == want) return __uint_as_float((unsigned)v);
  }
}

// Raw workgroup barrier: drains LDS (lgkm) only — publishes/prefetches stay
// in flight across it.
__device__ __forceinline__ void bar() {
  asm volatile("s_waitcnt lgkmcnt(0)" ::: "memory");
  __builtin_amdgcn_s_barrier();
  asm volatile("" ::: "memory");
}

// ---- named-register weight fragments + anti-rematerialization pin ----------
#define DECL_W8(p) float4 p##0, p##1, p##2, p##3, p##4, p##5, p##6, p##7
#define LOAD_W8(p, src) do { const float4* _s = (const float4*)(src); \
  p##0=_s[0]; p##1=_s[1]; p##2=_s[2]; p##3=_s[3]; \
  p##4=_s[4]; p##5=_s[5]; p##6=_s[6]; p##7=_s[7]; } while (0)
#define PIN4(v4) asm volatile("" : "+v"((v4).x), "+v"((v4).y), \
                                   "+v"((v4).z), "+v"((v4).w))
#define PIN_W8(p) do { PIN4(p##0); PIN4(p##1); PIN4(p##2); PIN4(p##3); \
  PIN4(p##4); PIN4(p##5); PIN4(p##6); PIN4(p##7); } while (0)
#define FMA4(acc, W_, H_) do { acc = fmaf((W_).x, (H_).x, acc); \
  acc = fmaf((W_).y, (H_).y, acc); acc = fmaf((W_).z, (H_).z, acc); \
  acc = fmaf((W_).w, (H_).w, acc); } while (0)

// X[t][k] = emb[tokens[t]][k], as float4
__global__ void gather_emb(const int* __restrict__ tokens,
                           const float4* __restrict__ emb4,
                           float4* __restrict__ X4) {
  int i = blockIdx.x * 256 + threadIdx.x;   // i < 4096*128
  int t = i >> 7;
  int q = i & 127;
  X4[i] = emb4[(long)tokens[t] * 128 + q];
}

// P[t][j] = bias_ih[j] + bias_hh[j] + sum_k X[src(t)][k] * W[j][k]
__global__ __launch_bounds__(256) void gemm_proj(
    const float* __restrict__ Xf, const float* __restrict__ Xb, int revb,
    const float* __restrict__ Wf, const float* __restrict__ Wb,
    const float* __restrict__ bihf, const float* __restrict__ bhhf,
    const float* __restrict__ bihb, const float* __restrict__ bhhb,
    float* __restrict__ Pf, float* __restrict__ Pb, int K)
{
  const int dirb = blockIdx.z;
  const float* X  = dirb ? Xb : Xf;
  const float* W  = dirb ? Wb : Wf;
  const float* bih = dirb ? bihb : bihf;
  const float* bhh = dirb ? bhhb : bhhf;
  float* Pp = dirb ? Pb : Pf;
  const int rev = dirb ? revb : 0;

  const int bn = blockIdx.x;   // N tile (16)
  const int bm = blockIdx.y;   // M tile (64)
  const int tid = threadIdx.x;
  const int tx = tid & 15, ty = tid >> 4;

  __shared__ float Xs[16][68];
  __shared__ float Ws[16][68];

  float acc[4][4] = {{0.f}};

  const int lrow = tid >> 2;
  const int lk4  = (tid & 3) * 4;
  const int xrow = bm * 64 + lrow;
  const int xsrc = rev ? (4095 - xrow) : xrow;
  const float* xptr = X + (long)xsrc * K + lk4;
  const float* wptr = W + (long)(bn * 64 + lrow) * K + lk4;

  for (int k0 = 0; k0 < K; k0 += 16) {
    float4 xv = *(const float4*)(xptr + k0);
    float4 wv = *(const float4*)(wptr + k0);
    __syncthreads();
    Xs[lk4 + 0][lrow] = xv.x; Xs[lk4 + 1][lrow] = xv.y;
    Xs[lk4 + 2][lrow] = xv.z; Xs[lk4 + 3][lrow] = xv.w;
    Ws[lk4 + 0][lrow] = wv.x; Ws[lk4 + 1][lrow] = wv.y;
    Ws[lk4 + 2][lrow] = wv.z; Ws[lk4 + 3][lrow] = wv.w;
    __syncthreads();
    #pragma unroll
    for (int kk = 0; kk < 16; ++kk) {
      float4 a = *(const float4*)(&Xs[kk][ty * 4]);
      float4 b = *(const float4*)(&Ws[kk][tx * 4]);
      acc[0][0] = fmaf(a.x, b.x, acc[0][0]); acc[0][1] = fmaf(a.x, b.y, acc[0][1]);
      acc[0][2] = fmaf(a.x, b.z, acc[0][2]); acc[0][3] = fmaf(a.x, b.w, acc[0][3]);
      acc[1][0] = fmaf(a.y, b.x, acc[1][0]); acc[1][1] = fmaf(a.y, b.y, acc[1][1]);
      acc[1][2] = fmaf(a.y, b.z, acc[1][2]); acc[1][3] = fmaf(a.y, b.w, acc[1][3]);
      acc[2][0] = fmaf(a.z, b.x, acc[2][0]); acc[2][1] = fmaf(a.z, b.y, acc[2][1]);
      acc[2][2] = fmaf(a.z, b.z, acc[2][2]); acc[2][3] = fmaf(a.z, b.w, acc[2][3]);
      acc[3][0] = fmaf(a.w, b.x, acc[3][0]); acc[3][1] = fmaf(a.w, b.y, acc[3][1]);
      acc[3][2] = fmaf(a.w, b.z, acc[3][2]); acc[3][3] = fmaf(a.w, b.w, acc[3][3]);
    }
  }

  const int c0 = bn * 64 + tx * 4;
  #pragma unroll
  for (int i = 0; i < 4; ++i) {
    const int r = bm * 64 + ty * 4 + i;
    float4 o4;
    o4.x = acc[i][0] + bih[c0 + 0] + bhh[c0 + 0];
    o4.y = acc[i][1] + bih[c0 + 1] + bhh[c0 + 1];
    o4.z = acc[i][2] + bih[c0 + 2] + bhh[c0 + 2];
    o4.w = acc[i][3] + bih[c0 + 3] + bhh[c0 + 3];
    *(float4*)(&Pp[(long)r * 1024 + c0]) = o4;
  }
}

// Fused 2-layer bidirectional LSTM recurrence — R6 structure (best measured:
// 7064 us), plus a 2-deep P-value pipeline in L0 so the compiler's vmcnt wait
// for the P load never lands inside the C phase (issue->use distance = one
// full step ~4000cy >> ~900cy latency).
//
// 24 WGs (12/dir). Roles per direction: r 0-3 = L0 (64 cells each), r 4-11 =
// L1 (32 cells each, K=512). Wave discipline (R10 lesson): poller threads
// live in waves that never issue any store. Exchange: cadence-1 drained MALL
// probes + system-scope publishes. 2 lgkm-only barriers per step.
__global__ __launch_bounds__(512, 1) void lstm_fused(
    const float* __restrict__ P0f, const float* __restrict__ P0b,
    const float* __restrict__ Whh0f, const float* __restrict__ Whh0b,
    const float* __restrict__ Wih1f, const float* __restrict__ Whh1f,
    const float* __restrict__ bih1f, const float* __restrict__ bhh1f,
    const float* __restrict__ Wih1b, const float* __restrict__ Whh1b,
    const float* __restrict__ bih1b, const float* __restrict__ bhh1b,
    float* __restrict__ out,
    ull* __restrict__ ring0,    // h0 ring [2 dirs][4096][256]
    ull* __restrict__ h1x)      // h1 slots [2 dirs][2 par][256]
{
  const int bx = blockIdx.x;
  const int t  = threadIdx.x;
  const int d   = bx & 1;    // 0 = forward, 1 = backward
  const int sub = bx >> 1;   // role within direction, 0..11

  __shared__ float hx[512];        // L0: h[256]; L1: h0[s] ++ h1[s-1]
  __shared__ float part[8 * 264];  // [k-slice][row m=cell*4+gate], padded

  ull* ring = ring0 + (long)d * T_SEQ * 256;

  if (sub < 4) {
    // ======================= Layer 0 (4 WGs/dir, 64 cells) ==================
    const int w = sub;
    const int wbase = w * 64;
    const float* __restrict__ P = d ? P0b : P0f;
    const float* __restrict__ W = d ? Whh0b : Whh0f;

    const int kb = t >> 6;   // k-slice 0..7 (32 k each)
    const int jg = t & 63;   // cell served by this B-thread

    // Weight rows for (cell=jg, gate=0..3), k-slice kb, pinned in registers.
    DECL_W8(wa); DECL_W8(wb); DECL_W8(wc); DECL_W8(wd);
    LOAD_W8(wa, W + (long)(0 * 256 + wbase + jg) * 256 + kb * 32);
    LOAD_W8(wb, W + (long)(1 * 256 + wbase + jg) * 256 + kb * 32);
    LOAD_W8(wc, W + (long)(2 * 256 + wbase + jg) * 256 + kb * 32);
    LOAD_W8(wd, W + (long)(3 * 256 + wbase + jg) * 256 + kb * 32);
    PIN_W8(wa); PIN_W8(wb); PIN_W8(wc); PIN_W8(wd);

    // C-thread t<256 handles row m=t: cell=t>>2, gate=t&3.
    const long pj = (long)((t & 3) * 256 + wbase + (t >> 2));

    // 2-deep P pipeline: P(s) consumed at C(s); P(s+2) issued at A(s).
    float pv_cur = 0.0f, pv_nx = 0.0f, c_prev = 0.0f;
    if (t < 256) {
      pv_cur = P[pj];
      pv_nx  = P[1024 + pj];
      hx[t] = 0.0f;
    }

    for (int s = 0; s < T_SEQ; ++s) {
      // -------- A: dedicated pollers fetch sibling h(s-1) ------------------
      if (s > 0 && t >= 256 && t < 448) {
        const int q = t - 256;
        const int pcell = (q < wbase) ? q : q + 64;
        hx[pcell] = poll_mall(ring + (long)(s - 1) * 256 + pcell, (unsigned)s);
      }
      float pv_nn = 0.0f;
      if (t < 256 && s + 2 < T_SEQ) pv_nn = P[(long)(s + 2) * 1024 + pj];
      bar();   // Y: hx(s-1) complete (pollers + prev combine's own-cell write)

      // -------- B: matvec from pinned-register weights ---------------------
      float a0 = 0.f, a1 = 0.f, a2 = 0.f, a3 = 0.f;
      const float4* h4 = (const float4*)&hx[kb * 32];
      #define L0STEP(q) do { float4 hv = h4[q]; FMA4(a0, wa##q, hv); \
        FMA4(a1, wb##q, hv); FMA4(a2, wc##q, hv); FMA4(a3, wd##q, hv); } while (0)
      L0STEP(0); L0STEP(1); L0STEP(2); L0STEP(3);
      L0STEP(4); L0STEP(5); L0STEP(6); L0STEP(7);
      #undef L0STEP
      float4 av; av.x = a0; av.y = a1; av.z = a2; av.w = a3;
      *(float4*)(&part[kb * 264 + jg * 4]) = av;   // rows m=jg*4+gate
      bar();   // 2: part[] complete

      // -------- C: activation + in-wave quad combine + publish -------------
      if (t < 256) {
        float g = pv_cur;
        #pragma unroll
        for (int q = 0; q < 8; ++q) g += part[q * 264 + t];
        float act = ((t & 3) == 2) ? tanhf(g) : sigmoidf_(g);
        float y  = __shfl_xor(act, 1);
        float zx = __shfl_xor(act, 2);
        float zy = __shfl_xor(y, 2);
        const bool l1b = (t & 1), h1b = (t & 2);
        float i_ = h1b ? (l1b ? zy : zx) : (l1b ? y : act);
        float f_ = h1b ? (l1b ? zx : zy) : (l1b ? act : y);
        float g_ = h1b ? (l1b ? y : act) : (l1b ? zy : zx);
        float o_ = h1b ? (l1b ? act : y) : (l1b ? zx : zy);
        float c = f_ * c_prev + i_ * g_;
        c_prev = c;
        float h = o_ * tanhf(c);
        pv_cur = pv_nx;
        pv_nx  = pv_nn;
        if ((t & 3) == 0) {
          const int gc = wbase + (t >> 2);
          hx[gc] = h;                                   // own-cell LDS bypass
          st_mall(ring + (long)s * 256 + gc, pack_h(s + 1, h));
          if (s == T_SEQ - 1) {
            out[d * 256 + gc] = c;            // cell_memories layer 0
            out[1024 + d * 256 + gc] = h;     // hidden_states layer 0
          }
        }
      }
      // no barrier here: next iteration's barY orders C writes vs B reads.
    }
  } else {
    // ======================= Layer 1 (8 WGs/dir, 32 cells) ==================
    const int w1 = sub - 4;   // 0..7
    const int wbase1 = w1 * 32;
    const float* __restrict__ Wih = d ? Wih1b : Wih1f;
    const float* __restrict__ Whh = d ? Whh1b : Whh1f;
    const float* __restrict__ bih = d ? bih1b : bih1f;
    const float* __restrict__ bhh = d ? bhh1b : bhh1f;
    ull* slot = h1x + d * 512;            // [parity][256]
    float* hout = d ? (out + 2048 + (long)4095 * 512 + 256) : (out + 2048);
    const long hstr = d ? -512 : 512;

    const int kb = t >> 6;   // k-slice 0..7 (64 k each of combined K=512)
    const int jg = t & 63;   // -> 2 rows m = jg*2, jg*2+1 (m in [0,128))

    const int m0 = jg * 2, m1 = m0 + 1;
    const int j0 = (m0 & 3) * 256 + wbase1 + (m0 >> 2);
    const int j1 = (m1 & 3) * 256 + wbase1 + (m1 >> 2);
    const float* s0 = (kb < 4) ? (Wih + (long)j0 * 256 + kb * 64)
                               : (Whh + (long)j0 * 256 + (kb - 4) * 64);
    const float* s1 = (kb < 4) ? (Wih + (long)j1 * 256 + kb * 64)
                               : (Whh + (long)j1 * 256 + (kb - 4) * 64);
    DECL_W8(ua); DECL_W8(ub); DECL_W8(uc); DECL_W8(ud);
    LOAD_W8(ua, s0); LOAD_W8(ub, s0 + 32);
    LOAD_W8(uc, s1); LOAD_W8(ud, s1 + 32);
    PIN_W8(ua); PIN_W8(ub); PIN_W8(uc); PIN_W8(ud);

    float bsum = 0.0f, c_prev = 0.0f;
    if (t < 128) {   // C-thread t handles row m=t: cell=t>>2, gate=t&3
      const int j = (t & 3) * 256 + wbase1 + (t >> 2);
      bsum = bih[j] + bhh[j];
      if ((t & 3) == 0) hx[256 + wbase1 + (t >> 2)] = 0.0f;  // own h1(-1)=0
    }

    for (int s = 0; s < T_SEQ; ++s) {
      // -------- A: poll h0(s) (256) + sibling h1(s-1) (224) ----------------
      if (t >= 128 && t < 384) {
        const int c0_ = t - 128;
        hx[c0_] = poll_mall(ring + (long)s * 256 + c0_, (unsigned)(s + 1));
      } else {
        int q1 = -1;
        if (t < 128) { if ((t & 3) != 0) q1 = (t >> 2) * 3 + (t & 3) - 1; }
        else q1 = 96 + (t - 384);
        if (q1 >= 0) {
          const int pc1 = (q1 < wbase1) ? q1 : q1 + 32;
          hx[256 + pc1] = poll_mall(slot + ((s + 1) & 1) * 256 + pc1,
                                    (unsigned)s);
        }
      }
      bar();   // Y

      // -------- B: matvec over K=512 ---------------------------------------
      float a0 = 0.f, a1 = 0.f;
      const float4* h4 = (const float4*)&hx[kb * 64];
      #define L1STEPA(q) do { float4 hv = h4[q];     FMA4(a0, ua##q, hv); \
        FMA4(a1, uc##q, hv); } while (0)
      #define L1STEPB(q) do { float4 hv = h4[8 + q]; FMA4(a0, ub##q, hv); \
        FMA4(a1, ud##q, hv); } while (0)
      L1STEPA(0); L1STEPA(1); L1STEPA(2); L1STEPA(3);
      L1STEPA(4); L1STEPA(5); L1STEPA(6); L1STEPA(7);
      L1STEPB(0); L1STEPB(1); L1STEPB(2); L1STEPB(3);
      L1STEPB(4); L1STEPB(5); L1STEPB(6); L1STEPB(7);
      #undef L1STEPA
      #undef L1STEPB
      float2 av2; av2.x = a0; av2.y = a1;
      *(float2*)(&part[kb * 264 + jg * 2]) = av2;
      bar();   // 2

      // -------- C: activation + quad combine + publish ---------------------
      if (t < 128) {
        float g = bsum;
        #pragma unroll
        for (int q = 0; q < 8; ++q) g += part[q * 264 + t];
        float act = ((t & 3) == 2) ? tanhf(g) : sigmoidf_(g);
        float y  = __shfl_xor(act, 1);
        float zx = __shfl_xor(act, 2);
        float zy = __shfl_xor(y, 2);
        const bool l1b = (t & 1), h1b = (t & 2);
        float i_ = h1b ? (l1b ? zy : zx) : (l1b ? y : act);
        float f_ = h1b ? (l1b ? zx : zy) : (l1b ? act : y);
        float g_ = h1b ? (l1b ? y : act) : (l1b ? zy : zx);
        float o_ = h1b ? (l1b ? act : y) : (l1b ? zx : zy);
        float c = f_ * c_prev + i_ * g_;
        c_prev = c;
        float h = o_ * tanhf(c);
        if ((t & 3) == 0) {
          const int gc = wbase1 + (t >> 2);
          hx[256 + gc] = h;                            // own-cell LDS bypass
          st_mall(&slot[(s & 1) * 256 + gc], pack_h(s + 1, h));
          hout[(long)s * hstr + gc] = h;
          if (s == T_SEQ - 1) {
            out[512 + d * 256 + gc] = c;          // cell_memories layer 1
            out[1024 + 512 + d * 256 + gc] = h;   // hidden_states layer 1
          }
        }
      }
    }
  }
}

extern "C" void kernel_launch(void* const* d_in, const int* in_sizes, int n_in,
                              void* d_out, int out_size, void* d_ws, size_t ws_size,
                              hipStream_t stream) {
  const int*   tokens = (const int*)d_in[0];
  const float* emb    = (const float*)d_in[1];
  const float* fWih0 = (const float*)d_in[2];
  const float* fWhh0 = (const float*)d_in[3];
  const float* fbih0 = (const float*)d_in[4];
  const float* fbhh0 = (const float*)d_in[5];
  const float* fWih1 = (const float*)d_in[6];
  const float* fWhh1 = (const float*)d_in[7];
  const float* fbih1 = (const float*)d_in[8];
  const float* fbhh1 = (const float*)d_in[9];
  const float* bWih0 = (const float*)d_in[10];
  const float* bWhh0 = (const float*)d_in[11];
  const float* bbih0 = (const float*)d_in[12];
  const float* bbhh0 = (const float*)d_in[13];
  const float* bWih1 = (const float*)d_in[14];
  const float* bWhh1 = (const float*)d_in[15];
  const float* bbih1 = (const float*)d_in[16];
  const float* bbhh1 = (const float*)d_in[17];

  float* out = (float*)d_out;
  float* ws  = (float*)d_ws;

  // Workspace layout (float offsets):
  //   [0, 4194304)          h0 rings [2 dirs][4096][256] u64 (16 MB); X
  //                         overlaps the first 8 MB (dead after gemm_proj,
  //                         rings memset afterwards)
  //   [4194304,  8388608)   P0f (4096x1024)
  //   [8388608, 12582912)   P0b (4096x1024)
  //   [12582912, 12584960)  h1x [2 dirs][2 par][256] u64 (8 KB)
  float* X   = ws;
  float* P0f = ws + 4194304;
  float* P0b = ws + 8388608;
  ull* ring0 = (ull*)ws;
  ull* h1x   = (ull*)(ws + 12582912);

  gather_emb<<<2048, 256, 0, stream>>>(tokens, (const float4*)emb, (float4*)X);

  // Layer 0 input projections (K=512); b-direction reads X time-reversed.
  gemm_proj<<<dim3(16, 64, 2), 256, 0, stream>>>(
      X, X, 1, fWih0, bWih0, fbih0, fbhh0, bbih0, bbhh0, P0f, P0b, 512);

  // Reset exchange buffers (tag 0 = "not ready" / "h(-1)=0").
  hipMemsetAsync(ring0, 0, (size_t)2 * T_SEQ * 256 * sizeof(ull), stream);
  hipMemsetAsync(h1x, 0, 1024 * sizeof(ull), stream);

  // Fused recurrence: 24 WGs (12 per direction), placement-independent.
  lstm_fused<<<dim3(24), 512, 0, stream>>>(
      P0f, P0b, fWhh0, bWhh0,
      fWih1, fWhh1, fbih1, fbhh1,
      bWih1, bWhh1, bbih1, bbhh1,
      out, ring0, h1x);
}